// Round 1
// baseline (431.300 us; speedup 1.0000x reference)
//
#include <hip/hip_runtime.h>
#include <cstddef>

// Problem constants
#define NB 256
#define NS 20
#define NL 512
#define ND 128
#define NH 768
#define ROWE (NS*(ND+NH))   // 17920 floats per output row

// ---------------------------------------------------------------------------
// K1: per-b block. se = embs[skills[b]] -> LDS + write to out[:, s*896+0..127].
//     q[b,s,h] = sum_d se[s,d]*W[d,h]  -> ws.
// 256 threads = 4 waves; wave w owns s in [5w,5w+5), lane owns h in {lane+64c}.
// ---------------------------------------------------------------------------
extern "C" __global__ __launch_bounds__(256)
void k1_q(const int* __restrict__ skills, const float* __restrict__ embs,
          const float* __restrict__ W, float* __restrict__ q,
          float* __restrict__ out)
{
    __shared__ float se[NS*ND];   // [20][128]
    __shared__ int   sk[NS];
    const int b = blockIdx.x, t = threadIdx.x;
    if (t < NS) sk[t] = skills[b*NS + t];
    __syncthreads();
    for (int idx = t; idx < NS*ND; idx += 256) {
        const int s = idx >> 7, d = idx & (ND-1);
        const float v = embs[(size_t)sk[s]*ND + d];
        se[idx] = v;
        out[(size_t)b*ROWE + (size_t)s*(ND+NH) + d] = v;   // se part of concat
    }
    __syncthreads();

    const int w = t >> 6, lane = t & 63;
    float acc[5][12];
    #pragma unroll
    for (int i = 0; i < 5; ++i)
        #pragma unroll
        for (int c = 0; c < 12; ++c) acc[i][c] = 0.f;

    const float* Wl = W + lane;
    for (int d4 = 0; d4 < ND/4; ++d4) {
        float4 sv[5];
        #pragma unroll
        for (int i = 0; i < 5; ++i)
            sv[i] = *(const float4*)&se[(5*w + i)*ND + 4*d4];
        #pragma unroll
        for (int r = 0; r < 4; ++r) {
            const float* wr = Wl + (size_t)(4*d4 + r)*NH;
            float wv[12];
            #pragma unroll
            for (int c = 0; c < 12; ++c) wv[c] = wr[64*c];
            #pragma unroll
            for (int i = 0; i < 5; ++i) {
                const float s_ = (r==0)?sv[i].x:(r==1)?sv[i].y:(r==2)?sv[i].z:sv[i].w;
                #pragma unroll
                for (int c = 0; c < 12; ++c) acc[i][c] += s_*wv[c];
            }
        }
    }
    #pragma unroll
    for (int i = 0; i < 5; ++i)
        #pragma unroll
        for (int c = 0; c < 12; ++c)
            q[((size_t)b*NS + 5*w + i)*NH + lane + 64*c] = acc[i][c];
}

// ---------------------------------------------------------------------------
// K2: scores[b,s,l] = sum_h q[b,s,h]*desc[b,l,h].
// Grid (NB, 2): block handles 256 l (= lhalf*256 .. +255) x all 20 s.
// 128 threads: tx = t&63 (l = tx+64j, j<4), ty = t>>6 (s = ty*10+i, i<10).
// desc k-tile (KT=64) staged in LDS, XOR-swizzled; q via lane-uniform global
// float4 loads (off the LDS pipe).
// ---------------------------------------------------------------------------
#define KT 64
extern "C" __global__ __launch_bounds__(128)
void k2_scores(const float* __restrict__ q, const float* __restrict__ desc,
               float* __restrict__ scores)
{
    __shared__ float dt[256*68];   // [256 rows][64 k + 4 pad], k XOR-swizzled
    const int b = blockIdx.x, lh = blockIdx.y;
    const int t = threadIdx.x, tx = t & 63, ty = t >> 6;

    float acc[4][10];
    #pragma unroll
    for (int j = 0; j < 4; ++j)
        #pragma unroll
        for (int i = 0; i < 10; ++i) acc[j][i] = 0.f;

    const float* descb = desc + ((size_t)b*NL + (size_t)lh*256)*NH;
    const float* qb    = q    + (size_t)b*NS*NH;
    const int swz = (tx & 3) << 4;   // read-side swizzle (row&3 == tx&3)

    for (int kb = 0; kb < NH; kb += KT) {
        __syncthreads();
        // stage desc[256][KT] -> LDS (4096 float4, 32 per thread)
        #pragma unroll
        for (int i = 0; i < 32; ++i) {
            const int vec = t + 128*i;
            const int row = vec >> 4, kq = vec & 15;
            const int k4 = kq*4;
            const int kk = k4 ^ ((row & 3) << 4);
            const float4 v = *(const float4*)&descb[(size_t)row*NH + kb + k4];
            *(float4*)&dt[row*68 + kk] = v;
        }
        __syncthreads();
        #pragma unroll 4
        for (int k4 = 0; k4 < KT; k4 += 4) {
            float4 dv[4];
            #pragma unroll
            for (int j = 0; j < 4; ++j) {
                const int row = tx + 64*j;
                dv[j] = *(const float4*)&dt[row*68 + (k4 ^ swz)];
            }
            #pragma unroll
            for (int i = 0; i < 10; ++i) {
                const float4 qv = *(const float4*)&qb[(size_t)(ty*10 + i)*NH + kb + k4];
                #pragma unroll
                for (int j = 0; j < 4; ++j)
                    acc[j][i] += dv[j].x*qv.x + dv[j].y*qv.y
                               + dv[j].z*qv.z + dv[j].w*qv.w;
            }
        }
    }
    #pragma unroll
    for (int i = 0; i < 10; ++i)
        #pragma unroll
        for (int j = 0; j < 4; ++j)
            scores[((size_t)b*NS + ty*10 + i)*NL + lh*256 + tx + 64*j] = acc[j][i];
}

// ---------------------------------------------------------------------------
// K3: softmax over l (512) per (b,s) row, in place. 5120 blocks x 128 threads.
// ---------------------------------------------------------------------------
extern "C" __global__ __launch_bounds__(128)
void k3_softmax(float* __restrict__ scores)
{
    const int r = blockIdx.x, t = threadIdx.x;
    float* row = scores + (size_t)r*NL;
    float4 v = *(const float4*)&row[t*4];
    float m = fmaxf(fmaxf(v.x, v.y), fmaxf(v.z, v.w));
    #pragma unroll
    for (int off = 32; off; off >>= 1) m = fmaxf(m, __shfl_xor(m, off));
    __shared__ float redm[2];
    if ((t & 63) == 0) redm[t >> 6] = m;
    __syncthreads();
    m = fmaxf(redm[0], redm[1]);

    const float e0 = expf(v.x - m), e1 = expf(v.y - m);
    const float e2 = expf(v.z - m), e3 = expf(v.w - m);
    float sum = e0 + e1 + e2 + e3;
    #pragma unroll
    for (int off = 32; off; off >>= 1) sum += __shfl_xor(sum, off);
    __shared__ float reds[2];
    if ((t & 63) == 0) reds[t >> 6] = sum;
    __syncthreads();
    sum = reds[0] + reds[1];
    const float inv = 1.0f / sum;
    float4 o; o.x = e0*inv; o.y = e1*inv; o.z = e2*inv; o.w = e3*inv;
    *(float4*)&row[t*4] = o;
}

// ---------------------------------------------------------------------------
// K4: out[b,s,h] = sum_l attn[b,s,l]*desc[b,l,h] -> out[:, s*896+128+h].
// One block per b, 512 threads: hh = t&255 (h = hh+256c, c<3),
// sg = t>>8 (s = sg*10+i, i<10). attn via lane-uniform float4 loads,
// desc coalesced. No LDS. HBM-bound on the desc re-read.
// ---------------------------------------------------------------------------
extern "C" __global__ __launch_bounds__(512)
void k4_out(const float* __restrict__ attn, const float* __restrict__ desc,
            float* __restrict__ out)
{
    const int b = blockIdx.x, t = threadIdx.x;
    const int hh = t & 255, sg = t >> 8;
    float acc[10][3];
    #pragma unroll
    for (int i = 0; i < 10; ++i)
        #pragma unroll
        for (int c = 0; c < 3; ++c) acc[i][c] = 0.f;

    const float* descb = desc + (size_t)b*NL*NH;
    const float* attnb = attn + (size_t)b*NS*NL + (size_t)sg*10*NL;

    #pragma unroll 2
    for (int l4 = 0; l4 < NL; l4 += 4) {
        float d0[4], d1[4], d2[4];
        #pragma unroll
        for (int rr = 0; rr < 4; ++rr) {
            const float* dr = descb + (size_t)(l4 + rr)*NH;
            d0[rr] = dr[hh]; d1[rr] = dr[hh + 256]; d2[rr] = dr[hh + 512];
        }
        #pragma unroll
        for (int i = 0; i < 10; ++i) {
            const float4 p = *(const float4*)&attnb[(size_t)i*NL + l4];
            acc[i][0] += p.x*d0[0] + p.y*d0[1] + p.z*d0[2] + p.w*d0[3];
            acc[i][1] += p.x*d1[0] + p.y*d1[1] + p.z*d1[2] + p.w*d1[3];
            acc[i][2] += p.x*d2[0] + p.y*d2[1] + p.z*d2[2] + p.w*d2[3];
        }
    }
    #pragma unroll
    for (int i = 0; i < 10; ++i)
        #pragma unroll
        for (int c = 0; c < 3; ++c)
            out[(size_t)b*ROWE + (size_t)(sg*10 + i)*(ND+NH) + ND + hh + 256*c]
                = acc[i][c];
}

// ---------------------------------------------------------------------------
extern "C" void kernel_launch(void* const* d_in, const int* in_sizes, int n_in,
                              void* d_out, int out_size, void* d_ws, size_t ws_size,
                              hipStream_t stream)
{
    const int*   skills = (const int*)  d_in[0];
    const float* desc   = (const float*)d_in[1];
    const float* embs   = (const float*)d_in[2];
    const float* W      = (const float*)d_in[3];
    float* out = (float*)d_out;

    float* q      = (float*)d_ws;                       // [NB][NS][NH]  15.7 MB
    float* scores = q + (size_t)NB*NS*NH;               // [NB][NS][NL]  10.5 MB

    k1_q      <<<NB,           256, 0, stream>>>(skills, embs, W, q, out);
    k2_scores <<<dim3(NB, 2),  128, 0, stream>>>(q, desc, scores);
    k3_softmax<<<NB*NS,        128, 0, stream>>>(scores);
    k4_out    <<<NB,           512, 0, stream>>>(scores, desc, out);
}

// Round 4
// 308.977 us; speedup vs baseline: 1.3959x; 1.3959x over previous
//
#include <hip/hip_runtime.h>
#include <cstddef>
#include <cstdint>

#define NB 256
#define NS 20
#define NL 512
#define ND 128
#define NH 768
#define ROWE (NS*(ND+NH))   // 17920 floats per output row

typedef __attribute__((ext_vector_type(4))) float  f32x4;
typedef __attribute__((ext_vector_type(8))) short  bf16x8;
typedef __attribute__((ext_vector_type(4))) unsigned short ushort4v;

#define MFMA16 __builtin_amdgcn_mfma_f32_16x16x32_bf16

__device__ __forceinline__ unsigned short bf16_rne(float v){
    unsigned u = __builtin_bit_cast(unsigned, v);
    u = (u + 0x7fffu + ((u>>16)&1u)) >> 16;
    return (unsigned short)u;
}
__device__ __forceinline__ float bf16f(unsigned short h){
    unsigned u = ((unsigned)h)<<16;
    return __builtin_bit_cast(float, u);
}

// ---------------------------------------------------------------------------
// K1: se = embs[skills[b]] -> out (concat left part);  q = se @ W -> bf16
// hi/lo arrays in ws. 256 blocks x 256 threads; wave w owns s in [5w,5w+5).
// ---------------------------------------------------------------------------
extern "C" __global__ __launch_bounds__(256)
void k1_q(const int* __restrict__ skills, const float* __restrict__ embs,
          const float* __restrict__ W,
          unsigned short* __restrict__ qhi, unsigned short* __restrict__ qlo,
          float* __restrict__ out)
{
    __shared__ float se[NS*ND];
    __shared__ int   sk[NS];
    const int b = blockIdx.x, t = threadIdx.x;
    if (t < NS) sk[t] = skills[b*NS + t];
    __syncthreads();
    for (int idx = t; idx < NS*ND; idx += 256) {
        const int s = idx >> 7, d = idx & (ND-1);
        const float v = embs[(size_t)sk[s]*ND + d];
        se[idx] = v;
        out[(size_t)b*ROWE + (size_t)s*(ND+NH) + d] = v;
    }
    __syncthreads();

    const int w = t >> 6, lane = t & 63;
    float acc[5][12];
    #pragma unroll
    for (int i = 0; i < 5; ++i)
        #pragma unroll
        for (int c = 0; c < 12; ++c) acc[i][c] = 0.f;

    const float* Wl = W + lane;
    for (int d4 = 0; d4 < ND/4; ++d4) {
        f32x4 sv[5];
        #pragma unroll
        for (int i = 0; i < 5; ++i)
            sv[i] = *(const f32x4*)&se[(5*w + i)*ND + 4*d4];
        #pragma unroll
        for (int r = 0; r < 4; ++r) {
            const float* wr = Wl + (size_t)(4*d4 + r)*NH;
            float wv[12];
            #pragma unroll
            for (int c = 0; c < 12; ++c) wv[c] = wr[64*c];
            #pragma unroll
            for (int i = 0; i < 5; ++i) {
                const float s_ = sv[i][r];
                #pragma unroll
                for (int c = 0; c < 12; ++c) acc[i][c] += s_*wv[c];
            }
        }
    }
    #pragma unroll
    for (int i = 0; i < 5; ++i)
        #pragma unroll
        for (int c = 0; c < 12; ++c) {
            const size_t idx = ((size_t)b*NS + 5*w + i)*NH + lane + 64*c;
            const float v = acc[i][c];
            const unsigned short hh = bf16_rne(v);
            qhi[idx] = hh;
            qlo[idx] = bf16_rne(v - bf16f(hh));
        }
}

// ---------------------------------------------------------------------------
// K2F: fused flash attention over l.  One block per b, 512 threads (8 waves).
// Wave w: st = w>>2 (s-tile 0/1), hq = w&3 (h-quarter). Waves 0,4 do QK+softmax.
//
// Per 32-l tile, staged in LDS:
//   dt_hi/dt_lo [32][DTP]  row-major bf16 hi/lo of desc tile (QK A-operand,
//                          contiguous ds_read_b128, pitch 776 hw -> 2-way banks)
//   vt [768][VTP]          TRANSPOSED hi tile: vt[h][pl], pl = P's natural
//                          in-register l-order (pl=8g+e <-> l = e<4 ? 4g+e
//                          : 16+4g+e-4).  PV A-operand = contiguous b128 read.
//
// QK: S^T[l][s] = 3x split-bf16 MFMA (A=desc rows, B=q rows, shared k-slot
// map -> exact pairing).  Softmax in-register (D: col=lane&15=s,
// row=4*(lane>>4)+reg=l; m89-verified).  PV: O^T = V^T * P^T  (A=vt rows,
// B=pa; pairing by construction).  D: col=s, row=h-offset -> lane owns one s,
// 4 contiguous h per MFMA -> float4 stores.
// ---------------------------------------------------------------------------
#define DTP 776                   // dt row pitch (halfwords): 1552 B, 2-way banks
#define VTP 40                    // vt row pitch (halfwords): 80 B, 16B-aligned

extern "C" __global__ __launch_bounds__(512)
void k2f(const unsigned short* __restrict__ qhi,
         const unsigned short* __restrict__ qlo,
         const float* __restrict__ desc, float* __restrict__ out)
{
    __shared__ unsigned short dt_hi[32*DTP];   // 49664 B
    __shared__ unsigned short dt_lo[32*DTP];   // 49664 B
    __shared__ unsigned short vt[NH*VTP];      // 61440 B
    __shared__ bf16x8 p_lds[2][64];            // 2048 B
    __shared__ float  f_lds[2][16];            // 128 B   (total 162944 B)

    const int b = blockIdx.x, t = threadIdx.x;
    const int w = t >> 6, L = t & 63;
    const int st = w >> 2, hq = w & 3;
    const bool qkw = ((w & 3) == 0);           // waves 0,4
    const int g = L >> 4, r16 = L & 15;

    const float* dsrc = desc + (size_t)b*NL*NH;

    // q row pointers (lane -> s column of its s-tile; clamp padded rows)
    const int s_in = 16*st + r16;
    const size_t qrow = ((size_t)b*NS + (s_in < NS ? s_in : NS-1))*(size_t)NH;
    const unsigned short* qh = qhi + qrow;
    const unsigned short* ql = qlo + qrow;

    f32x4 acc[12];
    #pragma unroll
    for (int ht = 0; ht < 12; ++ht) acc[ht] = (f32x4){0.f,0.f,0.f,0.f};

    float m_run = -1e30f, sum_run = 0.f;

    // --- staging registers: 12 float4 per thread (tile = 32x768 f32) ---
    f32x4 sreg[12];
    #pragma unroll
    for (int i = 0; i < 12; ++i) {
        const int v = t + 512*i;
        sreg[i] = *(const f32x4*)(dsrc + (size_t)v*4);   // tile 0
    }

    #pragma unroll 1
    for (int tt = 0; tt < NL/32; ++tt) {
        __syncthreads();   // prior-tile QK/PV done reading dt/vt

        // ---- stage write: f32 regs -> bf16 hi/lo dt + transposed vt ----
        #pragma unroll
        for (int i = 0; i < 12; ++i) {
            const int v = t + 512*i;
            const int l = v/192, h = 4*(v%192);
            ushort4v hi4, lo4;
            #pragma unroll
            for (int c = 0; c < 4; ++c) {
                const float x = sreg[i][c];
                const unsigned short hh = bf16_rne(x);
                hi4[c] = hh;
                lo4[c] = bf16_rne(x - bf16f(hh));
            }
            *(ushort4v*)&dt_hi[l*DTP + h] = hi4;
            *(ushort4v*)&dt_lo[l*DTP + h] = lo4;
            const int pl = (l < 16) ? (8*(l>>2) + (l&3))
                                    : (8*((l-16)>>2) + 4 + ((l-16)&3));
            #pragma unroll
            for (int c = 0; c < 4; ++c)
                vt[(h+c)*VTP + pl] = hi4[c];
        }
        __syncthreads();

        // ---- issue next tile's loads (in flight across QK+PV) ----
        if (tt < NL/32 - 1) {
            const float* nsrc = dsrc + (size_t)(tt+1)*32*NH;
            #pragma unroll
            for (int i = 0; i < 12; ++i) {
                const int v = t + 512*i;
                sreg[i] = *(const f32x4*)(nsrc + (size_t)v*4);
            }
        }

        // ---- QK^T + online softmax (waves 0 and 4 only) ----
        if (qkw) {
            f32x4 Se = (f32x4){0.f,0.f,0.f,0.f};
            f32x4 So = (f32x4){0.f,0.f,0.f,0.f};
            #pragma unroll 4
            for (int kb = 0; kb < NH/32; ++kb) {
                const int k0 = 32*kb;
                const bf16x8 Bh = *(const bf16x8*)&qh[k0 + 8*g];
                const bf16x8 Bl = *(const bf16x8*)&ql[k0 + 8*g];
                {   // m-tile 0: A row l = r16
                    const bf16x8 Ah = *(const bf16x8*)&dt_hi[r16*DTP + k0 + 8*g];
                    const bf16x8 Al = *(const bf16x8*)&dt_lo[r16*DTP + k0 + 8*g];
                    Se = MFMA16(Ah, Bh, Se, 0,0,0);
                    Se = MFMA16(Al, Bh, Se, 0,0,0);
                    Se = MFMA16(Ah, Bl, Se, 0,0,0);
                }
                {   // m-tile 1: A row l = 16 + r16
                    const bf16x8 Ah = *(const bf16x8*)&dt_hi[(16+r16)*DTP + k0 + 8*g];
                    const bf16x8 Al = *(const bf16x8*)&dt_lo[(16+r16)*DTP + k0 + 8*g];
                    So = MFMA16(Ah, Bh, So, 0,0,0);
                    So = MFMA16(Al, Bh, So, 0,0,0);
                    So = MFMA16(Ah, Bl, So, 0,0,0);
                }
            }
            // lane holds S^T[l = {4g+r, 16+4g+r}][s = r16]
            float pm = fmaxf(fmaxf(fmaxf(Se[0],Se[1]), fmaxf(Se[2],Se[3])),
                             fmaxf(fmaxf(So[0],So[1]), fmaxf(So[2],So[3])));
            pm = fmaxf(pm, __shfl_xor(pm, 16));
            pm = fmaxf(pm, __shfl_xor(pm, 32));
            const float mnew = fmaxf(m_run, pm);
            const float fsc  = __expf(m_run - mnew);
            float pe[4], po[4];
            #pragma unroll
            for (int r = 0; r < 4; ++r) {
                pe[r] = __expf(Se[r] - mnew);
                po[r] = __expf(So[r] - mnew);
            }
            float ts = (pe[0]+pe[1]+pe[2]+pe[3]) + (po[0]+po[1]+po[2]+po[3]);
            ts += __shfl_xor(ts, 16);
            ts += __shfl_xor(ts, 32);
            sum_run = sum_run*fsc + ts;
            m_run = mnew;
            bf16x8 pa;
            #pragma unroll
            for (int r = 0; r < 4; ++r) {
                pa[r]   = (short)bf16_rne(pe[r]);    // l = 4g+r
                pa[r+4] = (short)bf16_rne(po[r]);    // l = 16+4g+r
            }
            p_lds[st][L] = pa;
            if (L < 16) f_lds[st][L] = fsc;
        }
        __syncthreads();

        // ---- PV: all waves.  O^T = V^T * P^T ----
        const bf16x8 pa = p_lds[st][L];
        const float f  = f_lds[st][r16];
        #pragma unroll
        for (int ht = 0; ht < 12; ++ht) {
            acc[ht][0] *= f; acc[ht][1] *= f;
            acc[ht][2] *= f; acc[ht][3] *= f;
        }
        #pragma unroll
        for (int ht = 0; ht < 12; ++ht) {
            const int hrow = 16*(12*hq + ht) + r16;     // A row m = r16
            const bf16x8 av = *(const bf16x8*)&vt[hrow*VTP + 8*g];
            acc[ht] = MFMA16(av, pa, acc[ht], 0,0,0);
        }
    }

    // ---- epilogue: normalize and store ----
    __syncthreads();
    if (qkw && L < 16) f_lds[st][L] = 1.0f / sum_run;
    __syncthreads();
    const float inv = f_lds[st][r16];
    const int s = 16*st + r16;
    if (s < NS) {
        #pragma unroll
        for (int ht = 0; ht < 12; ++ht) {
            f32x4 o;
            o[0] = acc[ht][0]*inv; o[1] = acc[ht][1]*inv;
            o[2] = acc[ht][2]*inv; o[3] = acc[ht][3]*inv;
            // D row m = 4g+reg -> h = 16*(12hq+ht) + 4g + reg
            *(f32x4*)&out[(size_t)b*ROWE + (size_t)s*(ND+NH) + ND
                          + 16*(12*hq + ht) + 4*g] = o;
        }
    }
}

// ---------------------------------------------------------------------------
extern "C" void kernel_launch(void* const* d_in, const int* in_sizes, int n_in,
                              void* d_out, int out_size, void* d_ws, size_t ws_size,
                              hipStream_t stream)
{
    const int*   skills = (const int*)  d_in[0];
    const float* desc   = (const float*)d_in[1];
    const float* embs   = (const float*)d_in[2];
    const float* W      = (const float*)d_in[3];
    float* out = (float*)d_out;

    unsigned short* qhi = (unsigned short*)d_ws;              // [NB][NS][NH] bf16
    unsigned short* qlo = qhi + (size_t)NB*NS*NH;             // [NB][NS][NH] bf16

    k1_q<<<NB, 256, 0, stream>>>(skills, embs, W, qhi, qlo, out);
    k2f <<<NB, 512, 0, stream>>>(qhi, qlo, desc, out);
}

// Round 5
// 270.133 us; speedup vs baseline: 1.5966x; 1.1438x over previous
//
#include <hip/hip_runtime.h>
#include <cstddef>
#include <cstdint>

#define NB 256
#define NS 20
#define NL 512
#define ND 128
#define NH 768
#define ROWE (NS*(ND+NH))   // 17920 floats per output row

typedef __attribute__((ext_vector_type(4))) float  f32x4;
typedef __attribute__((ext_vector_type(8))) short  bf16x8;
typedef __attribute__((ext_vector_type(4))) short  short4v;
typedef __attribute__((ext_vector_type(4))) unsigned short ushort4v;
typedef __attribute__((ext_vector_type(8))) unsigned short ushort8v;

#define MFMA16 __builtin_amdgcn_mfma_f32_16x16x32_bf16

__device__ __forceinline__ unsigned short bf16_rne(float v){
    unsigned u = __builtin_bit_cast(unsigned, v);
    u = (u + 0x7fffu + ((u>>16)&1u)) >> 16;
    return (unsigned short)u;
}
__device__ __forceinline__ float bf16f(unsigned short h){
    unsigned u = ((unsigned)h)<<16;
    return __builtin_bit_cast(float, u);
}

// ---------------------------------------------------------------------------
// K1: se = embs[skills[b]] -> out (concat left part);  q = se @ W -> bf16
// hi/lo arrays in ws. 256 blocks x 256 threads; wave w owns s in [5w,5w+5).
// ---------------------------------------------------------------------------
extern "C" __global__ __launch_bounds__(256)
void k1_q(const int* __restrict__ skills, const float* __restrict__ embs,
          const float* __restrict__ W,
          unsigned short* __restrict__ qhi, unsigned short* __restrict__ qlo,
          float* __restrict__ out)
{
    __shared__ float se[NS*ND];
    __shared__ int   sk[NS];
    const int b = blockIdx.x, t = threadIdx.x;
    if (t < NS) sk[t] = skills[b*NS + t];
    __syncthreads();
    for (int idx = t; idx < NS*ND; idx += 256) {
        const int s = idx >> 7, d = idx & (ND-1);
        const float v = embs[(size_t)sk[s]*ND + d];
        se[idx] = v;
        out[(size_t)b*ROWE + (size_t)s*(ND+NH) + d] = v;
    }
    __syncthreads();

    const int w = t >> 6, lane = t & 63;
    float acc[5][12];
    #pragma unroll
    for (int i = 0; i < 5; ++i)
        #pragma unroll
        for (int c = 0; c < 12; ++c) acc[i][c] = 0.f;

    const float* Wl = W + lane;
    for (int d4 = 0; d4 < ND/4; ++d4) {
        f32x4 sv[5];
        #pragma unroll
        for (int i = 0; i < 5; ++i)
            sv[i] = *(const f32x4*)&se[(5*w + i)*ND + 4*d4];
        #pragma unroll
        for (int r = 0; r < 4; ++r) {
            const float* wr = Wl + (size_t)(4*d4 + r)*NH;
            float wv[12];
            #pragma unroll
            for (int c = 0; c < 12; ++c) wv[c] = wr[64*c];
            #pragma unroll
            for (int i = 0; i < 5; ++i) {
                const float s_ = sv[i][r];
                #pragma unroll
                for (int c = 0; c < 12; ++c) acc[i][c] += s_*wv[c];
            }
        }
    }
    #pragma unroll
    for (int i = 0; i < 5; ++i)
        #pragma unroll
        for (int c = 0; c < 12; ++c) {
            const size_t idx = ((size_t)b*NS + 5*w + i)*NH + lane + 64*c;
            const float v = acc[i][c];
            const unsigned short hh = bf16_rne(v);
            qhi[idx] = hh;
            qlo[idx] = bf16_rne(v - bf16f(hh));
        }
}

// ---------------------------------------------------------------------------
// K2F: fused flash attention over l.  One block per b, 512 threads (8 waves).
// Wave w: st = w>>2 (s-tile 0/1), hq = w&3 (h-quarter). Waves 0,4 do QK+softmax.
//
// Per 32-l tile, staged in LDS:
//   dt_hi/dt_lo [32][DTP]  row-major bf16 hi/lo of desc tile (QK A-operand,
//                          contiguous ds_read_b128; pitch 776 hw -> group step 1)
//   vt [768][VTP]          transposed hi tile vt[h][l], l in NATURAL order.
//                          Written from a SECOND global read (L2-hit): thread
//                          owns whole vt rows -> coalesced dword gathers +
//                          4 ds_write_b128 per row (pitch 40 hw, group step 5,
//                          conflict-free).  No scalar LDS scatter.
//
// QK: S^T[l][s] = 3x split-bf16 MFMA (A=desc rows, B=q rows, shared k-slot
// map -> exact pairing).  Softmax in-register (D: col=lane&15=s,
// row=4*(lane>>4)+reg=l; m89-verified).  P exchange via p2[st][s][v] vec4s in
// natural l-vec order v (l=4v..4v+3).  PV: O^T = V^T * P^T  (A=vt rows,
// B=pa; both natural l-order -> pairing by construction).  D: col=s,
// row=h-offset -> lane owns one s, 4 contiguous h per MFMA -> float4 stores.
// ---------------------------------------------------------------------------
#define DTP 776                   // dt row pitch (hw): 1552 B, b128 group step 1
#define VTP 40                    // vt row pitch (hw): 80 B, b128 group step 5

extern "C" __global__ __launch_bounds__(512)
void k2f(const unsigned short* __restrict__ qhi,
         const unsigned short* __restrict__ qlo,
         const float* __restrict__ desc, float* __restrict__ out)
{
    __shared__ unsigned short dt_hi[32*DTP];   // 49664 B
    __shared__ unsigned short dt_lo[32*DTP];   // 49664 B
    __shared__ unsigned short vt[NH*VTP];      // 61440 B
    __shared__ short4v p2[2][16][9];           // 2304 B  (pad 9 -> b64 step 9)
    __shared__ float  f_lds[2][16];            // 128 B   (total 163200 B)

    const int b = blockIdx.x, t = threadIdx.x;
    const int w = t >> 6, L = t & 63;
    const int st = w >> 2, hq = w & 3;
    const bool qkw = ((w & 3) == 0);           // waves 0,4
    const int g = L >> 4, r16 = L & 15;

    const float* dsrc = desc + (size_t)b*NL*NH;

    // q row pointers (lane -> s column of its s-tile; clamp padded rows)
    const int s_in = 16*st + r16;
    const size_t qrow = ((size_t)b*NS + (s_in < NS ? s_in : NS-1))*(size_t)NH;
    const unsigned short* qh = qhi + qrow;
    const unsigned short* ql = qlo + qrow;

    f32x4 acc[12];
    #pragma unroll
    for (int ht = 0; ht < 12; ++ht) acc[ht] = (f32x4){0.f,0.f,0.f,0.f};

    float m_run = -1e30f, sum_run = 0.f;

    // --- staging registers: 12 float4 per thread (tile = 32x768 f32) ---
    f32x4 sreg[12];
    #pragma unroll
    for (int i = 0; i < 12; ++i) {
        const int v = t + 512*i;
        sreg[i] = *(const f32x4*)(dsrc + (size_t)v*4);   // tile 0
    }

    #pragma unroll 1
    for (int tt = 0; tt < NL/32; ++tt) {
        __syncthreads();   // prior-tile QK/PV done reading dt/vt

        // ---- stage dt: f32 regs -> bf16 hi/lo row-major ----
        #pragma unroll
        for (int i = 0; i < 12; ++i) {
            const int v = t + 512*i;
            const int l = v/192, h = 4*(v%192);
            ushort4v hi4, lo4;
            #pragma unroll
            for (int c = 0; c < 4; ++c) {
                const float x = sreg[i][c];
                const unsigned short hh = bf16_rne(x);
                hi4[c] = hh;
                lo4[c] = bf16_rne(x - bf16f(hh));
            }
            *(ushort4v*)&dt_hi[l*DTP + h] = hi4;
            *(ushort4v*)&dt_lo[l*DTP + h] = lo4;
        }

        // ---- stage vt: transposed hi tile via second global read (L2-hit).
        //      Thread owns whole rows h: coalesced gathers + b128 writes. ----
        {
            const float* gsrc = dsrc + (size_t)tt*32*NH;
            // rows 0..255 by threads 0..255; rows 256..767 by all 512 threads
            #pragma unroll 1
            for (int rep = 0; rep < 2; ++rep) {
                const int h = (rep == 0) ? t : (256 + t);
                if (rep == 0 && t >= 256) continue;
                float v0[32];
                #pragma unroll
                for (int l = 0; l < 32; ++l)
                    v0[l] = gsrc[(size_t)l*NH + h];
                #pragma unroll
                for (int c4 = 0; c4 < 4; ++c4) {
                    ushort8v wv;
                    #pragma unroll
                    for (int e = 0; e < 8; ++e)
                        wv[e] = bf16_rne(v0[8*c4 + e]);
                    *(ushort8v*)&vt[h*VTP + 8*c4] = wv;
                }
            }
        }
        __syncthreads();

        // ---- issue next tile's loads (in flight across QK+PV) ----
        if (tt < NL/32 - 1) {
            const float* nsrc = dsrc + (size_t)(tt+1)*32*NH;
            #pragma unroll
            for (int i = 0; i < 12; ++i) {
                const int v = t + 512*i;
                sreg[i] = *(const f32x4*)(nsrc + (size_t)v*4);
            }
        }

        // ---- QK^T + online softmax (waves 0 and 4 only) ----
        if (qkw) {
            f32x4 Se = (f32x4){0.f,0.f,0.f,0.f};
            f32x4 So = (f32x4){0.f,0.f,0.f,0.f};
            #pragma unroll 4
            for (int kb = 0; kb < NH/32; ++kb) {
                const int k0 = 32*kb;
                const bf16x8 Bh = *(const bf16x8*)&qh[k0 + 8*g];
                const bf16x8 Bl = *(const bf16x8*)&ql[k0 + 8*g];
                {   // m-tile 0: A row l = r16
                    const bf16x8 Ah = *(const bf16x8*)&dt_hi[r16*DTP + k0 + 8*g];
                    const bf16x8 Al = *(const bf16x8*)&dt_lo[r16*DTP + k0 + 8*g];
                    Se = MFMA16(Ah, Bh, Se, 0,0,0);
                    Se = MFMA16(Al, Bh, Se, 0,0,0);
                    Se = MFMA16(Ah, Bl, Se, 0,0,0);
                }
                {   // m-tile 1: A row l = 16 + r16
                    const bf16x8 Ah = *(const bf16x8*)&dt_hi[(16+r16)*DTP + k0 + 8*g];
                    const bf16x8 Al = *(const bf16x8*)&dt_lo[(16+r16)*DTP + k0 + 8*g];
                    So = MFMA16(Ah, Bh, So, 0,0,0);
                    So = MFMA16(Al, Bh, So, 0,0,0);
                    So = MFMA16(Ah, Bl, So, 0,0,0);
                }
            }
            // lane holds S^T[l = {4g+r, 16+4g+r}][s = r16]
            float pm = fmaxf(fmaxf(fmaxf(Se[0],Se[1]), fmaxf(Se[2],Se[3])),
                             fmaxf(fmaxf(So[0],So[1]), fmaxf(So[2],So[3])));
            pm = fmaxf(pm, __shfl_xor(pm, 16));
            pm = fmaxf(pm, __shfl_xor(pm, 32));
            const float mnew = fmaxf(m_run, pm);
            const float fsc  = __expf(m_run - mnew);
            float pe[4], po[4];
            #pragma unroll
            for (int r = 0; r < 4; ++r) {
                pe[r] = __expf(Se[r] - mnew);
                po[r] = __expf(So[r] - mnew);
            }
            float ts = (pe[0]+pe[1]+pe[2]+pe[3]) + (po[0]+po[1]+po[2]+po[3]);
            ts += __shfl_xor(ts, 16);
            ts += __shfl_xor(ts, 32);
            sum_run = sum_run*fsc + ts;
            m_run = mnew;
            short4v pev, pov;
            #pragma unroll
            for (int r = 0; r < 4; ++r) {
                pev[r] = (short)bf16_rne(pe[r]);    // l = 4g+r   -> vec v = g
                pov[r] = (short)bf16_rne(po[r]);    // l = 16+4g+r-> vec v = 4+g
            }
            p2[st][r16][g]     = pev;
            p2[st][r16][4 + g] = pov;
            if (L < 16) f_lds[st][L] = fsc;
        }
        __syncthreads();

        // ---- PV: all waves.  O^T = V^T * P^T  (natural l-order pairing) ----
        const short4v a0 = p2[st][r16][2*g];
        const short4v a1 = p2[st][r16][2*g + 1];
        const bf16x8 pa = __builtin_shufflevector(a0, a1, 0,1,2,3,4,5,6,7);
        const float f  = f_lds[st][r16];
        #pragma unroll
        for (int ht = 0; ht < 12; ++ht) {
            acc[ht][0] *= f; acc[ht][1] *= f;
            acc[ht][2] *= f; acc[ht][3] *= f;
        }
        #pragma unroll
        for (int ht = 0; ht < 12; ++ht) {
            const int hrow = 16*(12*hq + ht) + r16;     // A row m = r16
            const bf16x8 av = *(const bf16x8*)&vt[hrow*VTP + 8*g];
            acc[ht] = MFMA16(av, pa, acc[ht], 0,0,0);
        }
    }

    // ---- epilogue: normalize and store ----
    __syncthreads();
    if (qkw && L < 16) f_lds[st][L] = 1.0f / sum_run;
    __syncthreads();
    const float inv = f_lds[st][r16];
    const int s = 16*st + r16;
    if (s < NS) {
        #pragma unroll
        for (int ht = 0; ht < 12; ++ht) {
            f32x4 o;
            o[0] = acc[ht][0]*inv; o[1] = acc[ht][1]*inv;
            o[2] = acc[ht][2]*inv; o[3] = acc[ht][3]*inv;
            // D row m = 4g+reg -> h = 16*(12hq+ht) + 4g + reg
            *(f32x4*)&out[(size_t)b*ROWE + (size_t)s*(ND+NH) + ND
                          + 16*(12*hq + ht) + 4*g] = o;
        }
    }
}

// ---------------------------------------------------------------------------
extern "C" void kernel_launch(void* const* d_in, const int* in_sizes, int n_in,
                              void* d_out, int out_size, void* d_ws, size_t ws_size,
                              hipStream_t stream)
{
    const int*   skills = (const int*)  d_in[0];
    const float* desc   = (const float*)d_in[1];
    const float* embs   = (const float*)d_in[2];
    const float* W      = (const float*)d_in[3];
    float* out = (float*)d_out;

    unsigned short* qhi = (unsigned short*)d_ws;              // [NB][NS][NH] bf16
    unsigned short* qlo = qhi + (size_t)NB*NS*NH;             // [NB][NS][NH] bf16

    k1_q<<<NB, 256, 0, stream>>>(skills, embs, W, qhi, qlo, out);
    k2f <<<NB, 512, 0, stream>>>(qhi, qlo, desc, out);
}

// Round 6
// 249.538 us; speedup vs baseline: 1.7284x; 1.0825x over previous
//
#include <hip/hip_runtime.h>
#include <cstddef>
#include <cstdint>

#define NB 256
#define NS 20
#define NL 512
#define ND 128
#define NH 768
#define ROWE (NS*(ND+NH))   // 17920 floats per output row

typedef __attribute__((ext_vector_type(4))) float  f32x4;
typedef __attribute__((ext_vector_type(8))) short  bf16x8;
typedef __attribute__((ext_vector_type(4))) short  short4v;
typedef __attribute__((ext_vector_type(4))) unsigned short ushort4v;
typedef __attribute__((ext_vector_type(8))) unsigned short ushort8v;

#define MFMA16 __builtin_amdgcn_mfma_f32_16x16x32_bf16

__device__ __forceinline__ unsigned short bf16_rne(float v){
    unsigned u = __builtin_bit_cast(unsigned, v);
    u = (u + 0x7fffu + ((u>>16)&1u)) >> 16;
    return (unsigned short)u;
}
__device__ __forceinline__ float bf16f(unsigned short h){
    unsigned u = ((unsigned)h)<<16;
    return __builtin_bit_cast(float, u);
}

// ---------------------------------------------------------------------------
// K1: se = embs[skills[b]] -> out (concat left part);  q = se @ W -> bf16
// hi/lo arrays in ws. 256 blocks x 256 threads; wave w owns s in [5w,5w+5).
// ---------------------------------------------------------------------------
extern "C" __global__ __launch_bounds__(256)
void k1_q(const int* __restrict__ skills, const float* __restrict__ embs,
          const float* __restrict__ W,
          unsigned short* __restrict__ qhi, unsigned short* __restrict__ qlo,
          float* __restrict__ out)
{
    __shared__ float se[NS*ND];
    __shared__ int   sk[NS];
    const int b = blockIdx.x, t = threadIdx.x;
    if (t < NS) sk[t] = skills[b*NS + t];
    __syncthreads();
    for (int idx = t; idx < NS*ND; idx += 256) {
        const int s = idx >> 7, d = idx & (ND-1);
        const float v = embs[(size_t)sk[s]*ND + d];
        se[idx] = v;
        out[(size_t)b*ROWE + (size_t)s*(ND+NH) + d] = v;
    }
    __syncthreads();

    const int w = t >> 6, lane = t & 63;
    float acc[5][12];
    #pragma unroll
    for (int i = 0; i < 5; ++i)
        #pragma unroll
        for (int c = 0; c < 12; ++c) acc[i][c] = 0.f;

    const float* Wl = W + lane;
    for (int d4 = 0; d4 < ND/4; ++d4) {
        f32x4 sv[5];
        #pragma unroll
        for (int i = 0; i < 5; ++i)
            sv[i] = *(const f32x4*)&se[(5*w + i)*ND + 4*d4];
        #pragma unroll
        for (int r = 0; r < 4; ++r) {
            const float* wr = Wl + (size_t)(4*d4 + r)*NH;
            float wv[12];
            #pragma unroll
            for (int c = 0; c < 12; ++c) wv[c] = wr[64*c];
            #pragma unroll
            for (int i = 0; i < 5; ++i) {
                const float s_ = sv[i][r];
                #pragma unroll
                for (int c = 0; c < 12; ++c) acc[i][c] += s_*wv[c];
            }
        }
    }
    #pragma unroll
    for (int i = 0; i < 5; ++i)
        #pragma unroll
        for (int c = 0; c < 12; ++c) {
            const size_t idx = ((size_t)b*NS + 5*w + i)*NH + lane + 64*c;
            const float v = acc[i][c];
            const unsigned short hh = bf16_rne(v);
            qhi[idx] = hh;
            qlo[idx] = bf16_rne(v - bf16f(hh));
        }
}

// ---------------------------------------------------------------------------
// K2F: fused flash attention over l.  One block per b, 512 threads (8 waves).
// Wave w: st = w>>2 (s-tile), kq = w&3 (QK k-quarter) = hq (PV h-quarter).
//
// Per 32-l tile:
//   dt_hi/dt_lo [32][DTP]  row-major bf16 hi/lo of desc tile (QK A-operand)
//   vtbuf [768][VTP]       transposed hi tile vt[h][l] (PV A-operand), built
//                          from a second (L2-hot) coalesced global read.
//                          Between QK and softmax the SAME region holds the
//                          QK partial-score scratch (16 KB overlay, barrier-
//                          separated).
//
// QK: all 8 waves; wave (st,kq) accumulates k in [192kq,192kq+192) with q
// hoisted to registers at kernel entry (zero global loads in loop); partials
// summed by kq=0 waves, then softmax in-register as before.
// PV: O^T = V^T * P^T, natural l-order pairing (unchanged from R5).
// ---------------------------------------------------------------------------
#define DTP 776                   // dt row pitch (hw): b128 group step 1
#define VTP 40                    // vt row pitch (hw): 80 B, group step 5

extern "C" __global__ __launch_bounds__(512)
void k2f(const unsigned short* __restrict__ qhi,
         const unsigned short* __restrict__ qlo,
         const float* __restrict__ desc, float* __restrict__ out)
{
    __shared__ __align__(16) unsigned short dt_hi[32*DTP];   // 49664 B
    __shared__ __align__(16) unsigned short dt_lo[32*DTP];   // 49664 B
    __shared__ __align__(16) unsigned short vtbuf[NH*VTP];   // 61440 B (+overlay)
    __shared__ short4v p2[2][16][9];                         // 2304 B
    __shared__ float  f_lds[2][16];                          // 128 B

    const int b = blockIdx.x, t = threadIdx.x;
    const int w = t >> 6, L = t & 63;
    const int st = w >> 2, kq = w & 3;        // kq doubles as PV h-quarter
    const int g = L >> 4, r16 = L & 15;

    const float* dsrc = desc + (size_t)b*NL*NH;

    // ---- hoist q (hi/lo) for this wave's k-quarter into registers ----
    const int s_in = 16*st + r16;
    const size_t qrow = ((size_t)b*NS + (s_in < NS ? s_in : NS-1))*(size_t)NH;
    bf16x8 qhreg[6], qlreg[6];
    #pragma unroll
    for (int kb = 0; kb < 6; ++kb) {
        const int k0 = 192*kq + 32*kb + 8*g;
        qhreg[kb] = *(const bf16x8*)&qhi[qrow + k0];
        qlreg[kb] = *(const bf16x8*)&qlo[qrow + k0];
    }

    f32x4 acc[12];
    #pragma unroll
    for (int ht = 0; ht < 12; ++ht) acc[ht] = (f32x4){0.f,0.f,0.f,0.f};

    float m_run = -1e30f, sum_run = 0.f;

    // --- staging registers: 12 float4 per thread (tile = 32x768 f32) ---
    f32x4 sreg[12];
    #pragma unroll
    for (int i = 0; i < 12; ++i) {
        const int v = t + 512*i;
        sreg[i] = *(const f32x4*)(dsrc + (size_t)v*4);   // tile 0
    }

    #pragma unroll 1
    for (int tt = 0; tt < NL/32; ++tt) {
        __syncthreads();   // B_a: prev tile's QK/PV reads complete

        // ---- stage dt: f32 regs -> bf16 hi/lo row-major ----
        #pragma unroll
        for (int i = 0; i < 12; ++i) {
            const int v = t + 512*i;
            const int l = v/192, h = 4*(v%192);
            ushort4v hi4, lo4;
            #pragma unroll
            for (int c = 0; c < 4; ++c) {
                const float x = sreg[i][c];
                const unsigned short hh = bf16_rne(x);
                hi4[c] = hh;
                lo4[c] = bf16_rne(x - bf16f(hh));
            }
            *(ushort4v*)&dt_hi[l*DTP + h] = hi4;
            *(ushort4v*)&dt_lo[l*DTP + h] = lo4;
        }

        // ---- issue vt gather (second read of this tile; L2-hot).
        //      1536 half-rows (16 l x 1 h); 3 per thread, balanced. ----
        float v0[3][16];
        {
            const float* gsrc = dsrc + (size_t)tt*32*NH;
            #pragma unroll
            for (int rep = 0; rep < 3; ++rep) {
                const int idx = 512*rep + t;
                const int lh  = (idx >= 768) ? 1 : 0;
                const int h   = idx - 768*lh;
                #pragma unroll
                for (int e = 0; e < 16; ++e)
                    v0[rep][e] = gsrc[(size_t)(16*lh + e)*NH + h];
            }
        }

        // ---- issue next tile's sreg loads (in flight across whole tile) ----
        if (tt < NL/32 - 1) {
            const float* nsrc = dsrc + (size_t)(tt+1)*32*NH;
            #pragma unroll
            for (int i = 0; i < 12; ++i) {
                const int v = t + 512*i;
                sreg[i] = *(const f32x4*)(nsrc + (size_t)v*4);
            }
        }
        __syncthreads();   // B_b: dt ready

        // ---- QK^T partial: wave (st,kq) covers k in [192kq, 192kq+192) ----
        f32x4 Se = (f32x4){0.f,0.f,0.f,0.f};
        f32x4 So = (f32x4){0.f,0.f,0.f,0.f};
        #pragma unroll
        for (int kb = 0; kb < 6; ++kb) {
            const int k0 = 192*kq + 32*kb;
            const bf16x8 Bh = qhreg[kb];
            const bf16x8 Bl = qlreg[kb];
            {   // m-tile 0: A row l = r16
                const bf16x8 Ah = *(const bf16x8*)&dt_hi[r16*DTP + k0 + 8*g];
                const bf16x8 Al = *(const bf16x8*)&dt_lo[r16*DTP + k0 + 8*g];
                Se = MFMA16(Ah, Bh, Se, 0,0,0);
                Se = MFMA16(Al, Bh, Se, 0,0,0);
                Se = MFMA16(Ah, Bl, Se, 0,0,0);
            }
            {   // m-tile 1: A row l = 16 + r16
                const bf16x8 Ah = *(const bf16x8*)&dt_hi[(16+r16)*DTP + k0 + 8*g];
                const bf16x8 Al = *(const bf16x8*)&dt_lo[(16+r16)*DTP + k0 + 8*g];
                So = MFMA16(Ah, Bh, So, 0,0,0);
                So = MFMA16(Al, Bh, So, 0,0,0);
                So = MFMA16(Ah, Bl, So, 0,0,0);
            }
        }
        // write partials to scratch (overlaid on vtbuf; vt not yet written)
        {
            f32x4* Sr = (f32x4*)vtbuf;
            const int i0 = ((st*4 + kq)*64 + L)*2;
            Sr[i0]     = Se;
            Sr[i0 + 1] = So;
        }
        __syncthreads();   // B_c: partials ready

        // ---- kq=0 waves: reduce partials + online softmax ----
        if (kq == 0) {
            {
                const f32x4* Sr = (const f32x4*)vtbuf;
                #pragma unroll
                for (int o = 1; o < 4; ++o) {
                    const int i0 = ((st*4 + o)*64 + L)*2;
                    Se += Sr[i0];
                    So += Sr[i0 + 1];
                }
            }
            // lane holds S^T[l = {4g+r, 16+4g+r}][s = r16]
            float pm = fmaxf(fmaxf(fmaxf(Se[0],Se[1]), fmaxf(Se[2],Se[3])),
                             fmaxf(fmaxf(So[0],So[1]), fmaxf(So[2],So[3])));
            pm = fmaxf(pm, __shfl_xor(pm, 16));
            pm = fmaxf(pm, __shfl_xor(pm, 32));
            const float mnew = fmaxf(m_run, pm);
            const float fsc  = __expf(m_run - mnew);
            float pe[4], po[4];
            #pragma unroll
            for (int r = 0; r < 4; ++r) {
                pe[r] = __expf(Se[r] - mnew);
                po[r] = __expf(So[r] - mnew);
            }
            float ts = (pe[0]+pe[1]+pe[2]+pe[3]) + (po[0]+po[1]+po[2]+po[3]);
            ts += __shfl_xor(ts, 16);
            ts += __shfl_xor(ts, 32);
            sum_run = sum_run*fsc + ts;
            m_run = mnew;
            short4v pev, pov;
            #pragma unroll
            for (int r = 0; r < 4; ++r) {
                pev[r] = (short)bf16_rne(pe[r]);    // l = 4g+r    -> vec g
                pov[r] = (short)bf16_rne(po[r]);    // l = 16+4g+r -> vec 4+g
            }
            p2[st][r16][g]     = pev;
            p2[st][r16][4 + g] = pov;
            if (L < 16) f_lds[st][L] = fsc;
        }
        __syncthreads();   // B_d: p2/f ready; scratch reads done -> vt free

        // ---- vt writes: v0 (gathered pre-QK) -> bf16 transposed tile ----
        #pragma unroll
        for (int rep = 0; rep < 3; ++rep) {
            const int idx = 512*rep + t;
            const int lh  = (idx >= 768) ? 1 : 0;
            const int h   = idx - 768*lh;
            ushort8v w0, w1;
            #pragma unroll
            for (int e = 0; e < 8; ++e) {
                w0[e] = bf16_rne(v0[rep][e]);
                w1[e] = bf16_rne(v0[rep][8 + e]);
            }
            *(ushort8v*)&vtbuf[h*VTP + 16*lh]     = w0;
            *(ushort8v*)&vtbuf[h*VTP + 16*lh + 8] = w1;
        }
        __syncthreads();   // B_e: vt ready

        // ---- PV: all waves.  O^T = V^T * P^T  (natural l-order pairing) ----
        const short4v a0 = p2[st][r16][2*g];
        const short4v a1 = p2[st][r16][2*g + 1];
        const bf16x8 pa = __builtin_shufflevector(a0, a1, 0,1,2,3,4,5,6,7);
        const float f  = f_lds[st][r16];
        #pragma unroll
        for (int ht = 0; ht < 12; ++ht) {
            acc[ht][0] *= f; acc[ht][1] *= f;
            acc[ht][2] *= f; acc[ht][3] *= f;
        }
        #pragma unroll
        for (int ht = 0; ht < 12; ++ht) {
            const int hrow = 16*(12*kq + ht) + r16;     // A row m = r16
            const bf16x8 av = *(const bf16x8*)&vtbuf[hrow*VTP + 8*g];
            acc[ht] = MFMA16(av, pa, acc[ht], 0,0,0);
        }
    }

    // ---- epilogue: normalize and store ----
    __syncthreads();
    if (kq == 0 && L < 16) f_lds[st][L] = 1.0f / sum_run;
    __syncthreads();
    const float inv = f_lds[st][r16];
    const int s = 16*st + r16;
    if (s < NS) {
        #pragma unroll
        for (int ht = 0; ht < 12; ++ht) {
            f32x4 o;
            o[0] = acc[ht][0]*inv; o[1] = acc[ht][1]*inv;
            o[2] = acc[ht][2]*inv; o[3] = acc[ht][3]*inv;
            // D row m = 4g+reg -> h = 16*(12kq+ht) + 4g + reg
            *(f32x4*)&out[(size_t)b*ROWE + (size_t)s*(ND+NH) + ND
                          + 16*(12*kq + ht) + 4*g] = o;
        }
    }
}

// ---------------------------------------------------------------------------
extern "C" void kernel_launch(void* const* d_in, const int* in_sizes, int n_in,
                              void* d_out, int out_size, void* d_ws, size_t ws_size,
                              hipStream_t stream)
{
    const int*   skills = (const int*)  d_in[0];
    const float* desc   = (const float*)d_in[1];
    const float* embs   = (const float*)d_in[2];
    const float* W      = (const float*)d_in[3];
    float* out = (float*)d_out;

    unsigned short* qhi = (unsigned short*)d_ws;              // [NB][NS][NH] bf16
    unsigned short* qlo = qhi + (size_t)NB*NS*NH;             // [NB][NS][NH] bf16

    k1_q<<<NB, 256, 0, stream>>>(skills, embs, W, qhi, qlo, out);
    k2f <<<NB, 512, 0, stream>>>(qhi, qlo, desc, out);
}

// Round 7
// 249.468 us; speedup vs baseline: 1.7289x; 1.0003x over previous
//
#include <hip/hip_runtime.h>
#include <cstddef>
#include <cstdint>

#define NB 256
#define NS 20
#define NL 512
#define ND 128
#define NH 768
#define ROWE (NS*(ND+NH))   // 17920 floats per output row

typedef __attribute__((ext_vector_type(4))) float  f32x4;
typedef __attribute__((ext_vector_type(8))) short  bf16x8;
typedef __attribute__((ext_vector_type(4))) short  short4v;
typedef __attribute__((ext_vector_type(4))) unsigned short ushort4v;
typedef __attribute__((ext_vector_type(8))) unsigned short ushort8v;

#define MFMA16 __builtin_amdgcn_mfma_f32_16x16x32_bf16

__device__ __forceinline__ unsigned short bf16_rne(float v){
    unsigned u = __builtin_bit_cast(unsigned, v);
    u = (u + 0x7fffu + ((u>>16)&1u)) >> 16;
    return (unsigned short)u;
}
__device__ __forceinline__ float bf16f(unsigned short h){
    unsigned u = ((unsigned)h)<<16;
    return __builtin_bit_cast(float, u);
}

// ---------------------------------------------------------------------------
// K1: se = embs[skills[b]] -> out (concat left part);  q = se @ W -> bf16
// hi/lo arrays in ws. 256 blocks x 256 threads; wave w owns s in [5w,5w+5).
// ---------------------------------------------------------------------------
extern "C" __global__ __launch_bounds__(256)
void k1_q(const int* __restrict__ skills, const float* __restrict__ embs,
          const float* __restrict__ W,
          unsigned short* __restrict__ qhi, unsigned short* __restrict__ qlo,
          float* __restrict__ out)
{
    __shared__ float se[NS*ND];
    __shared__ int   sk[NS];
    const int b = blockIdx.x, t = threadIdx.x;
    if (t < NS) sk[t] = skills[b*NS + t];
    __syncthreads();
    for (int idx = t; idx < NS*ND; idx += 256) {
        const int s = idx >> 7, d = idx & (ND-1);
        const float v = embs[(size_t)sk[s]*ND + d];
        se[idx] = v;
        out[(size_t)b*ROWE + (size_t)s*(ND+NH) + d] = v;
    }
    __syncthreads();

    const int w = t >> 6, lane = t & 63;
    float acc[5][12];
    #pragma unroll
    for (int i = 0; i < 5; ++i)
        #pragma unroll
        for (int c = 0; c < 12; ++c) acc[i][c] = 0.f;

    const float* Wl = W + lane;
    for (int d4 = 0; d4 < ND/4; ++d4) {
        f32x4 sv[5];
        #pragma unroll
        for (int i = 0; i < 5; ++i)
            sv[i] = *(const f32x4*)&se[(5*w + i)*ND + 4*d4];
        #pragma unroll
        for (int r = 0; r < 4; ++r) {
            const float* wr = Wl + (size_t)(4*d4 + r)*NH;
            float wv[12];
            #pragma unroll
            for (int c = 0; c < 12; ++c) wv[c] = wr[64*c];
            #pragma unroll
            for (int i = 0; i < 5; ++i) {
                const float s_ = sv[i][r];
                #pragma unroll
                for (int c = 0; c < 12; ++c) acc[i][c] += s_*wv[c];
            }
        }
    }
    #pragma unroll
    for (int i = 0; i < 5; ++i)
        #pragma unroll
        for (int c = 0; c < 12; ++c) {
            const size_t idx = ((size_t)b*NS + 5*w + i)*NH + lane + 64*c;
            const float v = acc[i][c];
            const unsigned short hh = bf16_rne(v);
            qhi[idx] = hh;
            qlo[idx] = bf16_rne(v - bf16f(hh));
        }
}

// ---------------------------------------------------------------------------
// K2F: fused flash attention over l.  One block per b, 512 threads (8 waves),
// __launch_bounds__(512,2): 2 waves/EU -> 256-VGPR budget so the full live
// set (sreg 48 + v0 48 + qreg 24 + acc 48) stays in registers (R6 spilled
// at the default 128 cap — that was the R6 regression vs prediction).
//
// Wave w: st = w>>2 (s-tile), kq = w&3 (QK k-quarter = PV h-quarter).
// Per 32-l tile:
//   dt_hi/dt_lo [32][DTP]  row-major bf16 hi/lo of desc tile (QK A-operand)
//   vtbuf [768][VTP]       transposed hi tile vt[h][l] (PV A-operand), from a
//                          second (L2-hot) coalesced global read; the same
//                          region holds the QK partial scratch between B_c/B_d.
// QK: all 8 waves, k-split 192 each, q hoisted to regs; partial reduce +
// in-register online softmax on kq=0 waves; PV: O^T = V^T * P^T.
// ---------------------------------------------------------------------------
#define DTP 776                   // dt row pitch (hw): b128 group step 1
#define VTP 40                    // vt row pitch (hw): 80 B, group step 5

extern "C" __global__ __launch_bounds__(512, 2)
void k2f(const unsigned short* __restrict__ qhi,
         const unsigned short* __restrict__ qlo,
         const float* __restrict__ desc, float* __restrict__ out)
{
    __shared__ __align__(16) unsigned short dt_hi[32*DTP];   // 49664 B
    __shared__ __align__(16) unsigned short dt_lo[32*DTP];   // 49664 B
    __shared__ __align__(16) unsigned short vtbuf[NH*VTP];   // 61440 B (+overlay)
    __shared__ short4v p2[2][16][9];                         // 2304 B
    __shared__ float  f_lds[2][16];                          // 128 B

    const int b = blockIdx.x, t = threadIdx.x;
    const int w = t >> 6, L = t & 63;
    const int st = w >> 2, kq = w & 3;        // kq doubles as PV h-quarter
    const int g = L >> 4, r16 = L & 15;

    const float* dsrc = desc + (size_t)b*NL*NH;

    // ---- hoist q (hi/lo) for this wave's k-quarter into registers ----
    const int s_in = 16*st + r16;
    const size_t qrow = ((size_t)b*NS + (s_in < NS ? s_in : NS-1))*(size_t)NH;
    bf16x8 qhreg[6], qlreg[6];
    #pragma unroll
    for (int kb = 0; kb < 6; ++kb) {
        const int k0 = 192*kq + 32*kb + 8*g;
        qhreg[kb] = *(const bf16x8*)&qhi[qrow + k0];
        qlreg[kb] = *(const bf16x8*)&qlo[qrow + k0];
    }

    f32x4 acc[12];
    #pragma unroll
    for (int ht = 0; ht < 12; ++ht) acc[ht] = (f32x4){0.f,0.f,0.f,0.f};

    float m_run = -1e30f, sum_run = 0.f;

    // --- staging registers: 12 float4 per thread (tile = 32x768 f32) ---
    f32x4 sreg[12];
    #pragma unroll
    for (int i = 0; i < 12; ++i) {
        const int v = t + 512*i;
        sreg[i] = *(const f32x4*)(dsrc + (size_t)v*4);   // tile 0
    }

    #pragma unroll 1
    for (int tt = 0; tt < NL/32; ++tt) {
        __syncthreads();   // B_a: prev tile's QK/PV reads complete

        // ---- stage dt: f32 regs -> bf16 hi/lo row-major ----
        #pragma unroll
        for (int i = 0; i < 12; ++i) {
            const int v = t + 512*i;
            const int l = v/192, h = 4*(v%192);
            ushort4v hi4, lo4;
            #pragma unroll
            for (int c = 0; c < 4; ++c) {
                const float x = sreg[i][c];
                const unsigned short hh = bf16_rne(x);
                hi4[c] = hh;
                lo4[c] = bf16_rne(x - bf16f(hh));
            }
            *(ushort4v*)&dt_hi[l*DTP + h] = hi4;
            *(ushort4v*)&dt_lo[l*DTP + h] = lo4;
        }

        // ---- issue vt gather (second read of this tile; L2-hot).
        //      1536 half-rows (16 l x 1 h); 3 per thread, balanced. ----
        float v0[3][16];
        {
            const float* gsrc = dsrc + (size_t)tt*32*NH;
            #pragma unroll
            for (int rep = 0; rep < 3; ++rep) {
                const int idx = 512*rep + t;
                const int lh  = (idx >= 768) ? 1 : 0;
                const int h   = idx - 768*lh;
                #pragma unroll
                for (int e = 0; e < 16; ++e)
                    v0[rep][e] = gsrc[(size_t)(16*lh + e)*NH + h];
            }
        }

        // ---- issue next tile's sreg loads (in flight across whole tile) ----
        if (tt < NL/32 - 1) {
            const float* nsrc = dsrc + (size_t)(tt+1)*32*NH;
            #pragma unroll
            for (int i = 0; i < 12; ++i) {
                const int v = t + 512*i;
                sreg[i] = *(const f32x4*)(nsrc + (size_t)v*4);
            }
        }
        __syncthreads();   // B_b: dt ready

        // ---- QK^T partial: wave (st,kq) covers k in [192kq, 192kq+192) ----
        f32x4 Se = (f32x4){0.f,0.f,0.f,0.f};
        f32x4 So = (f32x4){0.f,0.f,0.f,0.f};
        #pragma unroll
        for (int kb = 0; kb < 6; ++kb) {
            const int k0 = 192*kq + 32*kb;
            const bf16x8 Bh = qhreg[kb];
            const bf16x8 Bl = qlreg[kb];
            {   // m-tile 0: A row l = r16
                const bf16x8 Ah = *(const bf16x8*)&dt_hi[r16*DTP + k0 + 8*g];
                const bf16x8 Al = *(const bf16x8*)&dt_lo[r16*DTP + k0 + 8*g];
                Se = MFMA16(Ah, Bh, Se, 0,0,0);
                Se = MFMA16(Al, Bh, Se, 0,0,0);
                Se = MFMA16(Ah, Bl, Se, 0,0,0);
            }
            {   // m-tile 1: A row l = 16 + r16
                const bf16x8 Ah = *(const bf16x8*)&dt_hi[(16+r16)*DTP + k0 + 8*g];
                const bf16x8 Al = *(const bf16x8*)&dt_lo[(16+r16)*DTP + k0 + 8*g];
                So = MFMA16(Ah, Bh, So, 0,0,0);
                So = MFMA16(Al, Bh, So, 0,0,0);
                So = MFMA16(Ah, Bl, So, 0,0,0);
            }
        }
        // write partials to scratch (overlaid on vtbuf; vt not yet written)
        {
            f32x4* Sr = (f32x4*)vtbuf;
            const int i0 = ((st*4 + kq)*64 + L)*2;
            Sr[i0]     = Se;
            Sr[i0 + 1] = So;
        }
        __syncthreads();   // B_c: partials ready

        // ---- kq=0 waves: reduce partials + online softmax ----
        if (kq == 0) {
            {
                const f32x4* Sr = (const f32x4*)vtbuf;
                #pragma unroll
                for (int o = 1; o < 4; ++o) {
                    const int i0 = ((st*4 + o)*64 + L)*2;
                    Se += Sr[i0];
                    So += Sr[i0 + 1];
                }
            }
            // lane holds S^T[l = {4g+r, 16+4g+r}][s = r16]
            float pm = fmaxf(fmaxf(fmaxf(Se[0],Se[1]), fmaxf(Se[2],Se[3])),
                             fmaxf(fmaxf(So[0],So[1]), fmaxf(So[2],So[3])));
            pm = fmaxf(pm, __shfl_xor(pm, 16));
            pm = fmaxf(pm, __shfl_xor(pm, 32));
            const float mnew = fmaxf(m_run, pm);
            const float fsc  = __expf(m_run - mnew);
            float pe[4], po[4];
            #pragma unroll
            for (int r = 0; r < 4; ++r) {
                pe[r] = __expf(Se[r] - mnew);
                po[r] = __expf(So[r] - mnew);
            }
            float ts = (pe[0]+pe[1]+pe[2]+pe[3]) + (po[0]+po[1]+po[2]+po[3]);
            ts += __shfl_xor(ts, 16);
            ts += __shfl_xor(ts, 32);
            sum_run = sum_run*fsc + ts;
            m_run = mnew;
            short4v pev, pov;
            #pragma unroll
            for (int r = 0; r < 4; ++r) {
                pev[r] = (short)bf16_rne(pe[r]);    // l = 4g+r    -> vec g
                pov[r] = (short)bf16_rne(po[r]);    // l = 16+4g+r -> vec 4+g
            }
            p2[st][r16][g]     = pev;
            p2[st][r16][4 + g] = pov;
            if (L < 16) f_lds[st][L] = fsc;
        }
        __syncthreads();   // B_d: p2/f ready; scratch reads done -> vt free

        // ---- vt writes: v0 (gathered pre-QK) -> bf16 transposed tile ----
        #pragma unroll
        for (int rep = 0; rep < 3; ++rep) {
            const int idx = 512*rep + t;
            const int lh  = (idx >= 768) ? 1 : 0;
            const int h   = idx - 768*lh;
            ushort8v w0, w1;
            #pragma unroll
            for (int e = 0; e < 8; ++e) {
                w0[e] = bf16_rne(v0[rep][e]);
                w1[e] = bf16_rne(v0[rep][8 + e]);
            }
            *(ushort8v*)&vtbuf[h*VTP + 16*lh]     = w0;
            *(ushort8v*)&vtbuf[h*VTP + 16*lh + 8] = w1;
        }
        __syncthreads();   // B_e: vt ready

        // ---- PV: all waves.  O^T = V^T * P^T  (natural l-order pairing) ----
        const short4v a0 = p2[st][r16][2*g];
        const short4v a1 = p2[st][r16][2*g + 1];
        const bf16x8 pa = __builtin_shufflevector(a0, a1, 0,1,2,3,4,5,6,7);
        const float f  = f_lds[st][r16];
        #pragma unroll
        for (int ht = 0; ht < 12; ++ht) {
            acc[ht][0] *= f; acc[ht][1] *= f;
            acc[ht][2] *= f; acc[ht][3] *= f;
        }
        #pragma unroll
        for (int ht = 0; ht < 12; ++ht) {
            const int hrow = 16*(12*kq + ht) + r16;     // A row m = r16
            const bf16x8 av = *(const bf16x8*)&vtbuf[hrow*VTP + 8*g];
            acc[ht] = MFMA16(av, pa, acc[ht], 0,0,0);
        }
    }

    // ---- epilogue: normalize and store ----
    __syncthreads();
    if (kq == 0 && L < 16) f_lds[st][L] = 1.0f / sum_run;
    __syncthreads();
    const float inv = f_lds[st][r16];
    const int s = 16*st + r16;
    if (s < NS) {
        #pragma unroll
        for (int ht = 0; ht < 12; ++ht) {
            f32x4 o;
            o[0] = acc[ht][0]*inv; o[1] = acc[ht][1]*inv;
            o[2] = acc[ht][2]*inv; o[3] = acc[ht][3]*inv;
            // D row m = 4g+reg -> h = 16*(12kq+ht) + 4g + reg
            *(f32x4*)&out[(size_t)b*ROWE + (size_t)s*(ND+NH) + ND
                          + 16*(12*kq + ht) + 4*g] = o;
        }
    }
}

// ---------------------------------------------------------------------------
extern "C" void kernel_launch(void* const* d_in, const int* in_sizes, int n_in,
                              void* d_out, int out_size, void* d_ws, size_t ws_size,
                              hipStream_t stream)
{
    const int*   skills = (const int*)  d_in[0];
    const float* desc   = (const float*)d_in[1];
    const float* embs   = (const float*)d_in[2];
    const float* W      = (const float*)d_in[3];
    float* out = (float*)d_out;

    unsigned short* qhi = (unsigned short*)d_ws;              // [NB][NS][NH] bf16
    unsigned short* qlo = qhi + (size_t)NB*NS*NH;             // [NB][NS][NH] bf16

    k1_q<<<NB, 256, 0, stream>>>(skills, embs, W, qhi, qlo, out);
    k2f <<<NB, 512, 0, stream>>>(qhi, qlo, desc, out);
}